// Round 2
// baseline (185.560 us; speedup 1.0000x reference)
//
#include <hip/hip_runtime.h>
#include <hip/hip_fp16.h>

// BackProjectionLinear: out[b,p] = sum_d apod[d] * lerp(sino[b,d], k[p,d], a[p,d]) / 63.5
// B=4, N_DET=128, N_T=2048, pixels=65536.
//
// R2 design: latency-bound fix.
//  - 32 KB LDS (2 det x 4 batch x 2048 t, fp16) -> 4 blocks/CU resident.
//  - Block = 8 detectors (4 phases x 2) x 1024 pixels; grid 1024.
//  - lut float4 for phase p+1 prefetched BEFORE the staging barrier: the
//    vmcnt(0) drain at s_barrier completes them for free -> no exposed lut
//    latency in the gather loop (this was the R1 67us killer).
//  - XCD swizzle: all 64 pixel-tiles of one detector-octet land on one XCD
//    (bid%8 round-robin assumption) so the octet's 256KB of sino rows stays
//    in that XCD's 4MB L2 across restages.
//  - atomicAdd partials into zeroed d_out (16 octet-blocks per element).

#define NB      4
#define NDET    128
#define NT      2048
#define NPIX    65536
#define DPH     2                    // detectors staged per phase
#define NPHASE  4
#define DBLOCK  (DPH * NPHASE)       // 8 dets per block -> one 64B lut line/pixel
#define PTILE   1024
#define THREADS 256
#define PXPT    (PTILE / THREADS)    // 4 pixels per thread

__global__ __launch_bounds__(THREADS, 4)
void bp_kernel(const float* __restrict__ sino,
               const float* __restrict__ lut,
               float* __restrict__ out) {
    // LDS: [dl (0..1)][t (0..2047)][b (0..3)] fp16 = 32768 B
    __shared__ __half lds[DPH * NT * NB];

    const int tid = threadIdx.x;
    // XCD-locality swizzle: 1024 blocks, bid%8 ~ XCD. 128 blocks/XCD =
    // 2 octets x 64 tiles -> each octet's sino rows live in one XCD L2.
    const int bid   = blockIdx.x;
    const int xcd   = bid & 7;
    const int lid   = bid >> 3;            // 0..127
    const int octet = xcd * 2 + (lid >> 6);// 0..15
    const int tile  = lid & 63;            // 0..63
    const int d0    = octet * DBLOCK;
    const int px0   = tile * PTILE;

    float apod[DBLOCK];
#pragma unroll
    for (int j = 0; j < DBLOCK; ++j) {
        float x = (float)(d0 + j) * (6.28318530717958647692f / 127.0f);
        apod[j] = 0.5f - 0.5f * __cosf(x);
    }

    float acc[PXPT][NB];
#pragma unroll
    for (int i = 0; i < PXPT; ++i)
#pragma unroll
        for (int b = 0; b < NB; ++b) acc[i][b] = 0.0f;

    const float4* sino4 = (const float4*)sino;

    // lut pointer for (pixel, det-pair): one float4 = (k,a) x 2 dets
    auto lut4 = [&](int px, int d) {
        return (const float4*)(lut + ((size_t)px * NDET + d) * 2);
    };

    // phase-0 lut prefetch (completes under phase-0 staging's barrier drain)
    float4 Lcur[PXPT], Lnext[PXPT];
#pragma unroll
    for (int i = 0; i < PXPT; ++i)
        Lcur[i] = *lut4(px0 + tid + i * THREADS, d0);

    for (int phase = 0; phase < NPHASE; ++phase) {
        const int dg0 = d0 + phase * DPH;
        if (phase) __syncthreads();   // phase-1 readers done before overwrite

        // prefetch next phase's lut; drained by the barrier below -> free
        if (phase + 1 < NPHASE) {
#pragma unroll
            for (int i = 0; i < PXPT; ++i)
                Lnext[i] = *lut4(px0 + tid + i * THREADS, dg0 + DPH);
        }

        // ---- stage 2 det x 4 batch x 2048 t into LDS as fp16 ----
        for (int f = tid; f < DPH * NB * (NT / 4); f += THREADS) {
            int t4 = f & 511;          // float4 index along t
            int r  = f >> 9;           // 0..7
            int dl = r >> 2;           // 0..1
            int b  = r & 3;
            float4 v = sino4[((size_t)b * NDET + (dg0 + dl)) * (NT / 4) + t4];
            int t = t4 * 4;
            __half* dst = &lds[(dl * NT + t) * NB + b];
            dst[0 * NB] = __float2half(v.x);
            dst[1 * NB] = __float2half(v.y);
            dst[2 * NB] = __float2half(v.z);
            dst[3 * NB] = __float2half(v.w);
        }
        __syncthreads();

        // ---- gather + accumulate: 2 dets x 4 pixels/thread, lut in regs ----
#pragma unroll
        for (int i = 0; i < PXPT; ++i) {
            float4 L = Lcur[i];
            auto do_det = [&](float kf, float af, int dl, int j) {
                int k = (int)kf;
                unsigned uk = (unsigned)k;
                bool valid = uk < 2047u;         // covers k<0 via wraparound
                float w  = valid ? apod[j] : 0.0f;
                int  k0  = valid ? k : 0;
                const __half2* q = (const __half2*)&lds[(dl * NT + k0) * NB];
                __half2 s0a = q[0], s0b = q[1];  // t=k0,   b=0..3
                __half2 s1a = q[2], s1b = q[3];  // t=k0+1, b=0..3
                __half2 a2  = __float2half2_rn(af);
                __half2 ska = __hfma2(a2, __hsub2(s1a, s0a), s0a);
                __half2 skb = __hfma2(a2, __hsub2(s1b, s0b), s0b);
                float2 fa = __half22float2(ska);
                float2 fb = __half22float2(skb);
                acc[i][0] = fmaf(w, fa.x, acc[i][0]);
                acc[i][1] = fmaf(w, fa.y, acc[i][1]);
                acc[i][2] = fmaf(w, fb.x, acc[i][2]);
                acc[i][3] = fmaf(w, fb.y, acc[i][3]);
            };
            do_det(L.x, L.y, 0, phase * DPH + 0);
            do_det(L.z, L.w, 1, phase * DPH + 1);
        }
#pragma unroll
        for (int i = 0; i < PXPT; ++i) Lcur[i] = Lnext[i];
    }

    // ---- emit partial sums (16 octet-blocks contribute per output) ----
    const float inv_norm = 1.0f / 63.5f;   // sum(apod) == 63.5 exactly
#pragma unroll
    for (int i = 0; i < PXPT; ++i) {
        const int px = px0 + tid + i * THREADS;
#pragma unroll
        for (int b = 0; b < NB; ++b) {
            atomicAdd(&out[(size_t)b * NPIX + px], acc[i][b] * inv_norm);
        }
    }
}

extern "C" void kernel_launch(void* const* d_in, const int* in_sizes, int n_in,
                              void* d_out, int out_size, void* d_ws, size_t ws_size,
                              hipStream_t stream) {
    const float* sino = (const float*)d_in[0];
    const float* lut  = (const float*)d_in[1];
    float* out = (float*)d_out;

    hipMemsetAsync(d_out, 0, (size_t)out_size * sizeof(float), stream);

    // 16 octets x 64 pixel tiles = 1024 blocks -> 4 blocks/CU
    bp_kernel<<<dim3(1024), dim3(THREADS), 0, stream>>>(sino, lut, out);
}

// Round 3
// 139.772 us; speedup vs baseline: 1.3276x; 1.3276x over previous
//
#include <hip/hip_runtime.h>
#include <hip/hip_fp16.h>

// BackProjectionLinear: out[b,p] = sum_d apod[d] * lerp(sino[b,d], k[p,d], a[p,d]) / 63.5
// B=4, N_DET=128, N_T=2048, pixels=65536.
//
// R3: the R1/R2 FETCH bloat was lut lines fetched once PER PHASE (R1 2x=128MB,
// R2 3.4x=218MB). Fix: read each pixel's full 64B lut line (8 dets) into
// registers up front, consume across both phases -> lut HBM = 64MB exactly.
//  - Block = 8 dets x 2048 px, 512 thr, 2 phases x 4 dets, 64KB LDS, grid 512
//    (bid%16=octet -> octet pinned to one XCD's L2 for sino restage hits).
//  - LDS: two half2 planes [(b0,b1)],[(b2,b3)] indexed by t -> gather banks
//    t%32 (32 slots, ~4/bank avg ~1.58x) vs R1's (2t)%32 (16 slots, ~2.9x).
//  - Staging: thread owns one (det,t) for all 4 batches -> 4 coalesced dword
//    loads + 2 conflict-free aligned ds_write_b32 (R1/R2 did 8-way-conflicting
//    ds_write_b16).
//  - atomicAdd partials into zeroed d_out (16 octet-blocks per element).

#define NB      4
#define NDET    128
#define NT      2048
#define NPIX    65536
#define DPH     4                    // detectors staged per phase
#define NPHASE  2
#define DBLOCK  (DPH * NPHASE)       // 8 dets -> one 64B lut line per pixel
#define PTILE   2048
#define THREADS 512
#define PXPT    (PTILE / THREADS)    // 4 pixels per thread

__global__ __launch_bounds__(THREADS, 4)
void bp_kernel(const float* __restrict__ sino,
               const float* __restrict__ lut,
               float* __restrict__ out) {
    // [dl][plane][t]: plane0=(b0,b1) plane1=(b2,b3), half2 each. 64 KB.
    __shared__ __half2 lds[DPH][2][NT];

    const int tid   = threadIdx.x;
    const int octet = blockIdx.x & 15;   // bid%8 -> XCD: octet pinned to 1 XCD
    const int tile  = blockIdx.x >> 4;   // 0..31
    const int d0    = octet * DBLOCK;
    const int px0   = tile * PTILE;

    float apod[DBLOCK];
#pragma unroll
    for (int j = 0; j < DBLOCK; ++j) {
        float x = (float)(d0 + j) * (6.28318530717958647692f / 127.0f);
        apod[j] = 0.5f - 0.5f * __cosf(x);
    }

    // ---- full 64B lut line per pixel, loaded ONCE, held in registers ----
    // L[i][q]: q=0 -> dets d0+0,d0+1 ; q=1 -> d0+2,d0+3 ; q=2,3 -> phase 1.
    float4 L[PXPT][4];
#pragma unroll
    for (int i = 0; i < PXPT; ++i) {
        const float4* lp = (const float4*)
            (lut + ((size_t)(px0 + tid + i * THREADS) * NDET + d0) * 2);
#pragma unroll
        for (int q = 0; q < 4; ++q) L[i][q] = lp[q];
    }

    float acc[PXPT][NB];
#pragma unroll
    for (int i = 0; i < PXPT; ++i)
#pragma unroll
        for (int b = 0; b < NB; ++b) acc[i][b] = 0.0f;

    for (int phase = 0; phase < NPHASE; ++phase) {
        const int dg0 = d0 + phase * DPH;
        if (phase) __syncthreads();   // phase-0 readers done before overwrite

        // ---- stage: thread owns one (det,t) across all 4 batches ----
        // 4 coalesced dword loads (L2-hot sino) + 2 aligned ds_write_b32
        // (banks = t%32, consecutive lanes -> conflict-free).
        for (int f = tid; f < DPH * NT; f += THREADS) {
            int dl = f >> 11;          // 0..3
            int t  = f & (NT - 1);
            const float* src = sino + ((size_t)(dg0 + dl) * NT + t);
            float v0 = src[0];
            float v1 = src[(size_t)1 * NDET * NT];
            float v2 = src[(size_t)2 * NDET * NT];
            float v3 = src[(size_t)3 * NDET * NT];
            lds[dl][0][t] = __floats2half2_rn(v0, v1);
            lds[dl][1][t] = __floats2half2_rn(v2, v3);
        }
        __syncthreads();

        // ---- gather: 4 dets x 4 px/thread, lut already in registers ----
#pragma unroll
        for (int i = 0; i < PXPT; ++i) {
#pragma unroll
            for (int q = 0; q < 2; ++q) {
                float4 Lq = L[i][phase * 2 + q];
#pragma unroll
                for (int h = 0; h < 2; ++h) {
                    float kf = h ? Lq.z : Lq.x;
                    float af = h ? Lq.w : Lq.y;
                    int   dl = q * 2 + h;
                    int   j  = phase * DPH + dl;

                    int k = (int)kf;
                    unsigned uk = (unsigned)k;
                    bool valid = uk < (unsigned)(NT - 1);
                    float w  = valid ? apod[j] : 0.0f;
                    int  k0  = valid ? k : 0;
                    __half2 A  = lds[dl][0][k0];
                    __half2 Bv = lds[dl][0][k0 + 1];
                    __half2 C  = lds[dl][1][k0];
                    __half2 Dv = lds[dl][1][k0 + 1];
                    __half2 a2 = __float2half2_rn(af);
                    __half2 s01 = __hfma2(a2, __hsub2(Bv, A), A);
                    __half2 s23 = __hfma2(a2, __hsub2(Dv, C), C);
                    float2 f01 = __half22float2(s01);
                    float2 f23 = __half22float2(s23);
                    acc[i][0] = fmaf(w, f01.x, acc[i][0]);
                    acc[i][1] = fmaf(w, f01.y, acc[i][1]);
                    acc[i][2] = fmaf(w, f23.x, acc[i][2]);
                    acc[i][3] = fmaf(w, f23.y, acc[i][3]);
                }
            }
        }
    }

    // ---- emit partial sums (16 octet-blocks contribute per output) ----
    const float inv_norm = 1.0f / 63.5f;   // sum(apod) == 63.5 exactly
#pragma unroll
    for (int i = 0; i < PXPT; ++i) {
        const int px = px0 + tid + i * THREADS;
#pragma unroll
        for (int b = 0; b < NB; ++b) {
            atomicAdd(&out[(size_t)b * NPIX + px], acc[i][b] * inv_norm);
        }
    }
}

extern "C" void kernel_launch(void* const* d_in, const int* in_sizes, int n_in,
                              void* d_out, int out_size, void* d_ws, size_t ws_size,
                              hipStream_t stream) {
    const float* sino = (const float*)d_in[0];
    const float* lut  = (const float*)d_in[1];
    float* out = (float*)d_out;

    hipMemsetAsync(d_out, 0, (size_t)out_size * sizeof(float), stream);

    // 16 octets x 32 pixel tiles = 512 blocks -> 2 blocks/CU (64KB LDS each)
    bp_kernel<<<dim3(512), dim3(THREADS), 0, stream>>>(sino, lut, out);
}

// Round 4
// 129.697 us; speedup vs baseline: 1.4307x; 1.0777x over previous
//
#include <hip/hip_runtime.h>
#include <hip/hip_fp16.h>

// BackProjectionLinear: out[b,p] = sum_d apod[d] * lerp(sino[b,d], k[p,d], a[p,d]) / 63.5
// B=4, N_DET=128, N_T=2048, pixels=65536.
//
// R4: R3's VGPR_Count=64 + WRITE_SIZE 30MB showed the 16-float4 lut array
// spilled to scratch (gather loop serialized on scratch reloads).
// Fix: phase over BATCHES (2 per phase), not detectors -> every phase uses
// the pixel's whole 64B lut line, so live lut regs = PXPT(2) x 4 float4 =
// 32 VGPRs. No spill, no lut re-fetch.
//  - Block = 8 dets x 1024 px, 512 thr, 64KB LDS -> 2 blocks/CU.
//  - LDS: [dl (0..7)][t] half2 = (b_even, b_odd); gather bank = t%32,
//    random k -> ~2 lanes/bank = free (m136).
//  - Staging: thread owns (det, t4): 2 coalesced float4 loads + 1 aligned
//    ds_write_b128 (16B stride across lanes, conflict-free).
//  - bid%16 = octet; bid%8 ~ XCD -> each XCD serves 2 octets' sino rows
//    (512KB) from its L2 across all 64 pixel tiles.
//  - atomicAdd partials into zeroed d_out (16 octet-blocks per element).

#define NB      4
#define NDET    128
#define NT      2048
#define NPIX    65536
#define DBLOCK  8                    // dets per block = one 64B lut line
#define NPHASE  2                    // batch pairs: {0,1}, {2,3}
#define PTILE   1024
#define THREADS 512
#define PXPT    (PTILE / THREADS)    // 2 pixels per thread

__global__ __launch_bounds__(THREADS, 4)
void bp_kernel(const float* __restrict__ sino,
               const float* __restrict__ lut,
               float* __restrict__ out) {
    // [dl][t] half2 = sino[b_even], sino[b_odd] for current phase. 64 KB.
    __shared__ __half2 lds[DBLOCK][NT];

    const int tid   = threadIdx.x;
    const int octet = blockIdx.x & 15;   // bid%8 -> XCD pinning
    const int tile  = blockIdx.x >> 4;   // 0..63
    const int d0    = octet * DBLOCK;
    const int px0   = tile * PTILE;

    float apod[DBLOCK];
#pragma unroll
    for (int j = 0; j < DBLOCK; ++j) {
        float x = (float)(d0 + j) * (6.28318530717958647692f / 127.0f);
        apod[j] = 0.5f - 0.5f * __cosf(x);
    }

    // ---- full 64B lut line per pixel, loaded once, 32 VGPRs total ----
    float4 L[PXPT][4];   // L[i][q] = (k,a) for dets d0+2q, d0+2q+1
#pragma unroll
    for (int i = 0; i < PXPT; ++i) {
        const float4* lp = (const float4*)
            (lut + ((size_t)(px0 + tid + i * THREADS) * NDET + d0) * 2);
#pragma unroll
        for (int q = 0; q < 4; ++q) L[i][q] = lp[q];
    }

    float acc[PXPT][NB];
#pragma unroll
    for (int i = 0; i < PXPT; ++i)
#pragma unroll
        for (int b = 0; b < NB; ++b) acc[i][b] = 0.0f;

    for (int ph = 0; ph < NPHASE; ++ph) {
        const int b0 = ph * 2;            // batches b0, b0+1 this phase
        if (ph) __syncthreads();          // phase-0 readers done

        // ---- stage 8 dets x 2048 t x 2 batches as half2 ----
        // items: 8 dets x 512 t4 = 4096; 8 iters/thread.
        for (int f = tid; f < DBLOCK * (NT / 4); f += THREADS) {
            int dl = f >> 9;              // 0..7
            int t4 = f & 511;
            const float4* s4 = (const float4*)sino;
            float4 ve = s4[((size_t)(b0 + 0) * NDET + (d0 + dl)) * (NT / 4) + t4];
            float4 vo = s4[((size_t)(b0 + 1) * NDET + (d0 + dl)) * (NT / 4) + t4];
            __half2* dst = &lds[dl][t4 * 4];
            dst[0] = __floats2half2_rn(ve.x, vo.x);
            dst[1] = __floats2half2_rn(ve.y, vo.y);
            dst[2] = __floats2half2_rn(ve.z, vo.z);
            dst[3] = __floats2half2_rn(ve.w, vo.w);
        }
        __syncthreads();

        // ---- gather: 8 dets x 2 px/thread, lut in registers ----
#pragma unroll
        for (int i = 0; i < PXPT; ++i) {
#pragma unroll
            for (int q = 0; q < 4; ++q) {
                float4 Lq = L[i][q];
#pragma unroll
                for (int h = 0; h < 2; ++h) {
                    float kf = h ? Lq.z : Lq.x;
                    float af = h ? Lq.w : Lq.y;
                    int   dl = q * 2 + h;

                    int k = (int)kf;
                    unsigned uk = (unsigned)k;
                    bool valid = uk < (unsigned)(NT - 1);
                    float w  = valid ? apod[dl] : 0.0f;
                    int  k0  = valid ? k : 0;
                    __half2 s0 = lds[dl][k0];
                    __half2 s1 = lds[dl][k0 + 1];
                    __half2 a2 = __float2half2_rn(af);
                    __half2 sk = __hfma2(a2, __hsub2(s1, s0), s0);
                    float2  fv = __half22float2(sk);
                    acc[i][b0 + 0] = fmaf(w, fv.x, acc[i][b0 + 0]);
                    acc[i][b0 + 1] = fmaf(w, fv.y, acc[i][b0 + 1]);
                }
            }
        }
    }

    // ---- emit partial sums (16 octet-blocks contribute per output) ----
    const float inv_norm = 1.0f / 63.5f;   // sum(apod) == 63.5 exactly
#pragma unroll
    for (int i = 0; i < PXPT; ++i) {
        const int px = px0 + tid + i * THREADS;
#pragma unroll
        for (int b = 0; b < NB; ++b) {
            atomicAdd(&out[(size_t)b * NPIX + px], acc[i][b] * inv_norm);
        }
    }
}

extern "C" void kernel_launch(void* const* d_in, const int* in_sizes, int n_in,
                              void* d_out, int out_size, void* d_ws, size_t ws_size,
                              hipStream_t stream) {
    const float* sino = (const float*)d_in[0];
    const float* lut  = (const float*)d_in[1];
    float* out = (float*)d_out;

    hipMemsetAsync(d_out, 0, (size_t)out_size * sizeof(float), stream);

    // 16 octets x 64 pixel tiles = 1024 blocks -> 2 blocks/CU (64KB LDS)
    bp_kernel<<<dim3(1024), dim3(THREADS), 0, stream>>>(sino, lut, out);
}